// Round 9
// baseline (147.398 us; speedup 1.0000x reference)
//
#include <hip/hip_runtime.h>
#include <stdint.h>

#define BS 8192
#define DD 128

typedef __attribute__((ext_vector_type(8))) short short8;
typedef __attribute__((ext_vector_type(4))) float float4v;

#if __has_builtin(__builtin_amdgcn_exp2f)
#define EXP2(x) __builtin_amdgcn_exp2f(x)
#else
#define EXP2(x) exp2f(x)
#endif

__device__ __forceinline__ float bf2f(short s) {
  union { unsigned u; float f; } c;
  c.u = ((unsigned)(unsigned short)s) << 16;
  return c.f;
}
__device__ __forceinline__ short f2bf(float f) {
  union { float f; unsigned u; } c; c.f = f;
  unsigned u = c.u + 0x7FFFu + ((c.u >> 16) & 1u);
  return (short)(u >> 16);
}

// K1: normalize rows (f32 + packed-bf16 copies), per-class column sums, counts,
// f32 label mask mf[], zero-init of Zr/Ur/Vr/out (all stream-ordered before use).
__global__ __launch_bounds__(256) void k_norm(const float* __restrict__ data,
                                              const int* __restrict__ label,
                                              unsigned int* __restrict__ xnb32,
                                              float* __restrict__ xnf,
                                              float* __restrict__ gh,
                                              int* __restrict__ cnt,
                                              float* __restrict__ Zr,
                                              float* __restrict__ Ur,
                                              float* __restrict__ Vr,
                                              float* __restrict__ mf,
                                              float* __restrict__ out) {
  __shared__ float sh[256];
  __shared__ int shc[2];
  int tid = threadIdx.x, wave = tid >> 6, lane = tid & 63;
  if (tid < 2) shc[tid] = 0;
  sh[tid] = 0.f;
  if (tid < 32) {  // zero this block's accumulator slice (pre-poisoned 0xAA)
    int row = blockIdx.x * 32 + tid;
    Zr[row] = 0.f; Ur[row] = 0.f; Vr[row] = 0.f;
    mf[row] = (label[row] == 0) ? 1.f : 0.f;
  }
  if (blockIdx.x == 0 && tid == 0) out[0] = 0.f;
  __syncthreads();
  float a00 = 0.f, a01 = 0.f, a10 = 0.f, a11 = 0.f;
  int c0 = 0, c1 = 0;
  int rbase = blockIdx.x * 32 + wave * 8;
  for (int r = 0; r < 8; ++r) {
    int row = rbase + r;
    float2 v = *(const float2*)&data[row * DD + lane * 2];
    float ss = v.x * v.x + v.y * v.y;
    for (int off = 32; off; off >>= 1) ss += __shfl_xor(ss, off);
    float rn = 1.f / fmaxf(sqrtf(ss), 1e-12f);  // F.normalize eps clamp
    float x0 = v.x * rn, x1 = v.y * rn;
    *(float2*)&xnf[row * DD + lane * 2] = make_float2(x0, x1);
    unsigned int pk = (unsigned int)(unsigned short)f2bf(x0) |
                      ((unsigned int)(unsigned short)f2bf(x1) << 16);
    xnb32[row * 64 + lane] = pk;
    int lab = label[row];  // wave-uniform
    if (lab == 0) { a00 += x0; a01 += x1; c0++; }
    else          { a10 += x0; a11 += x1; c1++; }
  }
  atomicAdd(&sh[2 * lane], a00);
  atomicAdd(&sh[2 * lane + 1], a01);
  atomicAdd(&sh[128 + 2 * lane], a10);
  atomicAdd(&sh[128 + 2 * lane + 1], a11);
  if (lane == 0) { atomicAdd(&shc[0], c0); atomicAdd(&shc[1], c1); }
  __syncthreads();
  atomicAdd(&gh[tid], sh[tid]);
  if (tid < 2) atomicAdd(&cnt[tid], shc[tid]);
}

// ---- K3 helpers -----------------------------------------------------------
__device__ __forceinline__ void stage_tile(const char* srcbase, int j0,
                                           char* dstbase, int tid) {
  int rowloc = tid >> 4;
  int swz = (tid & 15) ^ rowloc;
  char* dst = dstbase + tid * 16;
#pragma unroll
  for (int p = 0; p < 4; ++p) {
    const char* src = srcbase + (size_t)(j0 + p * 16 + rowloc) * 256 + swz * 16;
    __builtin_amdgcn_global_load_lds(
        (const __attribute__((address_space(1))) void*)(uintptr_t)src,
        (__attribute__((address_space(3))) void*)(uintptr_t)(dst + p * 4096), 16, 0, 0);
  }
}

// Consume one 64x64 tile. Row sums -> registers. If DOCOL, per-wave col sums
// (valid row sums for cols J by Gram symmetry) -> plain LDS stores into
// colacc[wave][k*64 + jc16] — NO device atomics (R8: 6.3M contended atomicAdds
// to a 96KB region cross-XCD cost +19us; this replaces them entirely).
template <bool DOCOL>
__device__ __forceinline__ void consume64(const short* __restrict__ tile, int jt64,
                                          const float* __restrict__ mf,
                                          const short8 afrag[4], const float mrow[4],
                                          int wave, int quad, int col,
                                          float rZ[4], float rU[4], float rV[4],
                                          float* colacc) {
#pragma unroll
  for (int jo = 0; jo < 4; ++jo) {
    int jc16 = jo * 16 + col;
    float mcol = mf[jt64 + jc16];  // 1.0 if col j is class 0
    float4v c = {0.f, 0.f, 0.f, 0.f};
    const short* bp = tile + jc16 * DD;
#pragma unroll
    for (int t = 0; t < 4; ++t) {
      short8 b = *(const short8*)(bp + ((t * 4 + quad) ^ col) * 8);
      c = __builtin_amdgcn_mfma_f32_16x16x32_bf16(afrag[t], b, c, 0, 0, 0);
    }
    float cZ = 0.f, cU = 0.f, cV = 0.f;
#pragma unroll
    for (int r = 0; r < 4; ++r) {  // C/D: col=lane&15, row=quad*4+r (m89)
      float l = c[r], e = EXP2(l), el = e * l;  // log2-domain, fp32-safe
      rZ[r] += e; rU[r] += el; rV[r] += mcol * e;
      if (DOCOL) { cZ += e; cU += el; cV += mrow[r] * e; }
    }
    if (DOCOL) {
      cZ += __shfl_xor(cZ, 16); cZ += __shfl_xor(cZ, 32);
      cU += __shfl_xor(cU, 16); cU += __shfl_xor(cU, 32);
      cV += __shfl_xor(cV, 16); cV += __shfl_xor(cV, 32);
      if (quad == 0) {  // each (wave, jc16) slot written exactly once per tile
        colacc[wave * 192 + jc16] = cZ;
        colacc[wave * 192 + 64 + jc16] = cU;
        colacc[wave * 192 + 128 + jc16] = cV;
      }
    }
  }
}

// Sum the 4 wave-slots and write one coalesced 768B record to scratch.
// Called AFTER the barrier that ends the tile's consume (all colacc visible).
__device__ __forceinline__ void flush_col(const float* colacc, float* __restrict__ scr,
                                          int jt, int slot, int tid) {
  if (tid < 192) {
    float s = colacc[tid] + colacc[192 + tid] + colacc[384 + tid] + colacc[576 + tid];
    scr[((size_t)jt * 64 + slot) * 192 + tid] = s;  // [jt][slot][k*64+cj]
  }
}

// K3: SYMMETRIC flash Gram reductions (tiles 16384 -> 8384). Off-diag 64x64 tile
// computed once, credited to row-block (registers) and col-block (LDS->scratch,
// atomic-free). Coverage: row-tile it handles offsets o=1..64 (o=64 only for
// it<64) mod 128 — each unordered pair exactly once (R8-verified, absmax 0).
// Chassis: R5 dbuf loop; flushes piggyback on the existing two barriers
// (colacc WAR/RAW pairs all barrier-separated — checked per-buffer).
__global__ __launch_bounds__(256) void k_main(const unsigned short* __restrict__ xnb,
                                              const int* __restrict__ label,
                                              const float* __restrict__ mf,
                                              const float* __restrict__ scale,
                                              float* __restrict__ Zr,
                                              float* __restrict__ Ur,
                                              float* __restrict__ Vr,
                                              float* __restrict__ scr) {
  __shared__ short tileA[64 * DD];   // 16 KB
  __shared__ short tileB[64 * DD];   // 16 KB
  __shared__ float colA[4 * 192];    // 3 KB  per-wave col sums, tile A
  __shared__ float colB[4 * 192];    // 3 KB
  int tid = threadIdx.x, wave = tid >> 6, lane = tid & 63;
  int quad = lane >> 4, col = lane & 15;
  int it = blockIdx.x / 9;   // row-tile 0..127
  int sub = blockIdx.x % 9;  // 0..7 off-diag strips; 8 = diagonal
  float se2 = __expf(scale[0]) * 1.4426950408889634f;  // exp(scale)*log2(e)

  int rowbase = it * 64 + wave * 16;
  const short* ap = (const short*)xnb + (size_t)(rowbase + col) * DD;
  short8 afrag[4];
#pragma unroll
  for (int t = 0; t < 4; ++t) {
    short8 a = *(const short8*)(ap + t * 32 + quad * 8);
#pragma unroll
    for (int i = 0; i < 8; ++i) a[i] = f2bf(bf2f(a[i]) * se2);
    afrag[t] = a;
  }
  int labI[4];
  float mrow[4];
#pragma unroll
  for (int r = 0; r < 4; ++r) {
    int rr = rowbase + quad * 4 + r;
    labI[r] = label[rr];
    mrow[r] = mf[rr];
  }

  float rZ[4] = {}, rU[4] = {}, rV[4] = {};
  const char* srcbase = (const char*)xnb;

  if (sub == 8) {
    stage_tile(srcbase, it * 64, (char*)tileA, tid);
    __syncthreads();
    consume64<false>(tileA, it * 64, mf, afrag, mrow, wave, quad, col, rZ, rU, rV, nullptr);
  } else {
    int obase = sub * 8 + 1;  // offsets o = obase..obase+7 (max 64)
    stage_tile(srcbase, ((it + obase) & 127) * 64, (char*)tileA, tid);
    __syncthreads();
    for (int p = 0; p < 8; p += 2) {
      int oA = obase + p, oB = obase + p + 1;
      int jtA = (it + oA) & 127, jtB = (it + oB) & 127;
      int jtN = (it + obase + ((p + 2) & 7)) & 127;
      bool doA = oA < 64 || it < 64;   // o==64 pair owned by it<64 only
      bool doB = oB < 64 || it < 64;
      stage_tile(srcbase, jtB * 64, (char*)tileB, tid);
      if (doA)
        consume64<true>(tileA, jtA * 64, mf, afrag, mrow, wave, quad, col, rZ, rU, rV, colA);
      __syncthreads();  // tileB ready; colA complete across waves
      if (doA) flush_col(colA, scr, jtA, oA - 1, tid);
      stage_tile(srcbase, jtN * 64, (char*)tileA, tid);
      if (doB)
        consume64<true>(tileB, jtB * 64, mf, afrag, mrow, wave, quad, col, rZ, rU, rV, colB);
      __syncthreads();  // tileA(next) ready; colB complete
      if (doB) flush_col(colB, scr, jtB, oB - 1, tid);
    }
  }

  // row-side flush: reduce across the 16 col-lanes, then 3 atomics per row
#pragma unroll
  for (int r = 0; r < 4; ++r)
#pragma unroll
    for (int off = 1; off < 16; off <<= 1) {
      rZ[r] += __shfl_xor(rZ[r], off);
      rU[r] += __shfl_xor(rU[r], off);
      rV[r] += __shfl_xor(rV[r], off);
    }
  if (col == 0) {
#pragma unroll
    for (int r = 0; r < 4; ++r) {
      int row = rowbase + quad * 4 + r;
      float v = (labI[r] == 0) ? rV[r] : (rZ[r] - rV[r]);
      atomicAdd(&Zr[row], rZ[r]);
      atomicAdd(&Ur[row], rU[r] * 0.6931471805599453f);  // log2 -> nats
      atomicAdd(&Vr[row], v);
    }
  }
}

// K_red: fold scratch col records into Zr/Ur/Vr. 128 blocks x 1 wave; per col:
// sum slots 0..62 (+63 iff jt>=64 — slot 63 written only by it<64 pairs).
// Reads coalesced (64 consecutive floats per array per slot).
__global__ __launch_bounds__(64) void k_red(const float* __restrict__ scr,
                                            const float* __restrict__ mf,
                                            float* __restrict__ Zr,
                                            float* __restrict__ Ur,
                                            float* __restrict__ Vr) {
  int jt = blockIdx.x, cj = threadIdx.x;
  int smax = 63 + (jt >= 64 ? 1 : 0);
  float sZ = 0.f, sU = 0.f, sV = 0.f;
  const float* base = scr + (size_t)jt * 64 * 192;
  for (int sl = 0; sl < smax; ++sl) {
    const float* p = base + sl * 192;
    sZ += p[cj]; sU += p[64 + cj]; sV += p[128 + cj];
  }
  int j = jt * 64 + cj;
  float v = (mf[j] > 0.5f) ? sV : (sZ - sV);  // same-class sum for col j
  atomicAdd(&Zr[j], sZ);
  atomicAdd(&Ur[j], sU * 0.6931471805599453f);  // log2 -> nats
  atomicAdd(&Vr[j], v);
}

// K4: per-row loss. S,T via closed-form dots with class sums; M and log(Zq) cancel.
__global__ __launch_bounds__(256) void k_final(const float* __restrict__ xnf,
                                               const int* __restrict__ label,
                                               const float* __restrict__ scale,
                                               const float* __restrict__ gh,
                                               const int* __restrict__ cnt,
                                               const float* __restrict__ Zr,
                                               const float* __restrict__ Ur,
                                               const float* __restrict__ Vr,
                                               float* __restrict__ out) {
  __shared__ float bsum[4];
  int tid = threadIdx.x, wave = tid >> 6, lane = tid & 63;
  float se = __expf(scale[0]);
  float h0a = gh[2 * lane], h0b = gh[2 * lane + 1];
  float h1a = gh[128 + 2 * lane], h1b = gh[128 + 2 * lane + 1];
  float ga = h0a + h1a, gb = h0b + h1b;  // g = h0 + h1
  float c0 = (float)cnt[0], c1 = (float)cnt[1];
  float local = 0.f;
  int rbase = blockIdx.x * 32 + wave * 8;
  for (int r = 0; r < 8; ++r) {
    int row = rbase + r;
    float2 x = *(const float2*)&xnf[row * DD + lane * 2];
    int lab = label[row];
    float sg = x.x * ga + x.y * gb;
    float sh_ = (lab == 0) ? (x.x * h0a + x.y * h0b) : (x.x * h1a + x.y * h1b);
    for (int off = 32; off; off >>= 1) {
      sg += __shfl_xor(sg, off);
      sh_ += __shfl_xor(sh_, off);
    }
    if (lane == 0) {
      float cc = (lab == 0) ? c0 : c1;
      float a = __expf(1.f / cc);
      float Zq = cc * a + ((float)BS - cc);
      float S = se * sg, T = se * sh_;
      float Z = Zr[row], U = Ur[row], V = Vr[row];
      // loss_i = a/Zq - (S+(a-1)T)/Zq + U/Z - V/(c*Z)   (M_i, log Zq cancelled)
      local += a / Zq - (S + (a - 1.f) * T) / Zq + U / Z - V / (cc * Z);
    }
  }
  if (lane == 0) bsum[wave] = local;
  __syncthreads();
  if (tid == 0) {
    float s = bsum[0] + bsum[1] + bsum[2] + bsum[3];
    atomicAdd(out, s * (0.5f / (float)BS));
  }
}

extern "C" void kernel_launch(void* const* d_in, const int* in_sizes, int n_in,
                              void* d_out, int out_size, void* d_ws, size_t ws_size,
                              hipStream_t stream) {
  const float* data = (const float*)d_in[0];
  const float* scale = (const float*)d_in[1];
  const int* label = (const int*)d_in[2];
  char* ws = (char*)d_ws;
  // ws layout (bytes):
  //   0        xnb  bf16[8192*128]   2 MB
  //   2097152  xnf  f32 [8192*128]   4 MB
  //   6291456  Zr   f32 [8192]
  //   6324224  Ur   f32 [8192]
  //   6356992  Vr   f32 [8192]
  //   6389760  gh   f32 [256]
  //   6390784  cnt  int [2]
  //   6390800  mf   f32 [8192]
  //   8388608  scr  f32 [128][64][192]  6.29 MB col-sum scratch (slot o-1;
  //            every read slot written exactly once -> no zeroing needed)
  unsigned short* xnb = (unsigned short*)ws;
  unsigned int* xnb32 = (unsigned int*)ws;
  float* xnf = (float*)(ws + 2097152);
  float* Zr = (float*)(ws + 6291456);
  float* Ur = (float*)(ws + 6324224);
  float* Vr = (float*)(ws + 6356992);
  float* gh = (float*)(ws + 6389760);
  int* cnt = (int*)(ws + 6390784);
  float* mf = (float*)(ws + 6390800);
  float* scr = (float*)(ws + 8388608);

  // gh+cnt only (1032 B); Zr/Ur/Vr/mf + d_out are initialized inside k_norm
  hipMemsetAsync(ws + 6389760, 0, 1032, stream);

  k_norm<<<256, 256, 0, stream>>>(data, label, xnb32, xnf, gh, cnt, Zr, Ur, Vr, mf,
                                  (float*)d_out);
  k_main<<<128 * 9, 256, 0, stream>>>(xnb, label, mf, scale, Zr, Ur, Vr, scr);
  k_red<<<128, 64, 0, stream>>>(scr, mf, Zr, Ur, Vr);
  k_final<<<256, 256, 0, stream>>>(xnf, label, scale, gh, cnt, Zr, Ur, Vr, (float*)d_out);
}

// Round 10
// 122.196 us; speedup vs baseline: 1.2062x; 1.2062x over previous
//
#include <hip/hip_runtime.h>
#include <stdint.h>

#define BS 8192
#define DD 128

typedef __attribute__((ext_vector_type(8))) short short8;
typedef __attribute__((ext_vector_type(4))) float float4v;

#if __has_builtin(__builtin_amdgcn_exp2f)
#define EXP2(x) __builtin_amdgcn_exp2f(x)
#else
#define EXP2(x) exp2f(x)
#endif

__device__ __forceinline__ float bf2f(short s) {
  union { unsigned u; float f; } c;
  c.u = ((unsigned)(unsigned short)s) << 16;
  return c.f;
}
__device__ __forceinline__ short f2bf(float f) {
  union { float f; unsigned u; } c; c.f = f;
  unsigned u = c.u + 0x7FFFu + ((c.u >> 16) & 1u);
  return (short)(u >> 16);
}

// K1: normalize rows (f32 + packed-bf16 copies), per-class column sums, counts,
// zero-init of Zr/Ur/Vr/out (all stream-ordered before use).
__global__ __launch_bounds__(256) void k_norm(const float* __restrict__ data,
                                              const int* __restrict__ label,
                                              unsigned int* __restrict__ xnb32,
                                              float* __restrict__ xnf,
                                              float* __restrict__ gh,
                                              int* __restrict__ cnt,
                                              float* __restrict__ Zr,
                                              float* __restrict__ Ur,
                                              float* __restrict__ Vr,
                                              float* __restrict__ out) {
  __shared__ float sh[256];
  __shared__ int shc[2];
  int tid = threadIdx.x, wave = tid >> 6, lane = tid & 63;
  if (tid < 2) shc[tid] = 0;
  sh[tid] = 0.f;
  if (tid < 32) {  // zero this block's accumulator slice (pre-poisoned 0xAA)
    int row = blockIdx.x * 32 + tid;
    Zr[row] = 0.f; Ur[row] = 0.f; Vr[row] = 0.f;
  }
  if (blockIdx.x == 0 && tid == 0) out[0] = 0.f;
  __syncthreads();
  float a00 = 0.f, a01 = 0.f, a10 = 0.f, a11 = 0.f;
  int c0 = 0, c1 = 0;
  int rbase = blockIdx.x * 32 + wave * 8;
  for (int r = 0; r < 8; ++r) {
    int row = rbase + r;
    float2 v = *(const float2*)&data[row * DD + lane * 2];
    float ss = v.x * v.x + v.y * v.y;
    for (int off = 32; off; off >>= 1) ss += __shfl_xor(ss, off);
    float rn = 1.f / fmaxf(sqrtf(ss), 1e-12f);  // F.normalize eps clamp
    float x0 = v.x * rn, x1 = v.y * rn;
    *(float2*)&xnf[row * DD + lane * 2] = make_float2(x0, x1);
    unsigned int pk = (unsigned int)(unsigned short)f2bf(x0) |
                      ((unsigned int)(unsigned short)f2bf(x1) << 16);
    xnb32[row * 64 + lane] = pk;
    int lab = label[row];  // wave-uniform
    if (lab == 0) { a00 += x0; a01 += x1; c0++; }
    else          { a10 += x0; a11 += x1; c1++; }
  }
  atomicAdd(&sh[2 * lane], a00);
  atomicAdd(&sh[2 * lane + 1], a01);
  atomicAdd(&sh[128 + 2 * lane], a10);
  atomicAdd(&sh[128 + 2 * lane + 1], a11);
  if (lane == 0) { atomicAdd(&shc[0], c0); atomicAdd(&shc[1], c1); }
  __syncthreads();
  atomicAdd(&gh[tid], sh[tid]);
  if (tid < 2) atomicAdd(&cnt[tid], shc[tid]);
}

// K3: BARRIER-FREE single-wave pipeline.
// 10 rounds of evidence: every multi-wave LDS chassis is pinned at 41-50us by the
// block-wide vmcnt(0)+s_barrier convoy; register-prefetch variants die in the
// allocator (R6 VGPR=36 demotion, R7 spills). Here each BLOCK IS ONE WAVE with a
// private 3x4KB LDS ring staged by global_load_lds (DMA: outstanding loads hold
// NO VGPRs) and hand-placed `s_waitcnt vmcnt(N)` instead of barriers:
//   stage t+2 (4 DMAs) -> vmcnt(8) (drains ONLY tile t; 2 batches stay in
//   flight) -> 4x ds_read_b128 (XOR-swizzled, conflict-free) -> 16 MFMA
//   (64 rows x 16 cols x K=128) -> exp epilogue.
// The hot loop has NO global loads (col-class mask pre-packed into a 32-bit reg
// per lane), so the vmcnt stream is pure DMA and the waits are exact. Every
// wave free-runs: no convoy, 8 independent pipelines per CU.
__global__ __launch_bounds__(64) void k_main(const unsigned short* __restrict__ xnb,
                                             const int* __restrict__ label,
                                             const float* __restrict__ scale,
                                             float* __restrict__ Zr,
                                             float* __restrict__ Ur,
                                             float* __restrict__ Vr) {
  __shared__ char ldsb[3 * 4096];  // 3-deep ring of 16-col x 128 bf16 tiles
  int lane = threadIdx.x;          // 0..63 (one wave)
  int quad = lane >> 4, col = lane & 15;
  int rg = blockIdx.x >> 4;        // row-group 0..127 (64 rows)
  int sl = blockIdx.x & 15;        // col-slice 0..15 (512 cols)
  float se2 = __expf(scale[0]) * 1.4426950408889634f;  // exp(scale)*log2(e)
  int rowbase = rg * 64, jbase = sl * 512;
  const short* xs = (const short*)xnb;

  // col-class mask: bit t = (label[jbase + t*16 + col] == 0). 32 loads, pre-loop.
  unsigned mk = 0;
#pragma unroll
  for (int t = 0; t < 32; ++t)
    mk |= (label[jbase + t * 16 + col] == 0) ? (1u << t) : 0u;

  // A fragments: 4 rowsets of 16 rows; A[m=col][k=quad*8+i], ktiles t=0..3
  short8 afrag[4][4];
#pragma unroll
  for (int s = 0; s < 4; ++s) {
    const short* ap = xs + (size_t)(rowbase + s * 16 + col) * DD;
#pragma unroll
    for (int t = 0; t < 4; ++t) {
      short8 a = *(const short8*)(ap + t * 32 + quad * 8);
#pragma unroll
      for (int i = 0; i < 8; ++i) a[i] = f2bf(bf2f(a[i]) * se2);
      afrag[s][t] = a;
    }
  }

  // per-lane constant offsets
  // stage: DMA inst p stages tile-row r16=p*4+quad, chunk (col^r16) (XOR swizzle)
  int offp[4];
#pragma unroll
  for (int p = 0; p < 4; ++p) {
    int r16 = p * 4 + quad;
    offp[p] = r16 * 256 + ((col ^ r16) & 15) * 16;
  }
  // read: chunk (t*4+quad)^col of tile-row col -> conflict-free b128 (8 dw/bank)
  int boff[4];
#pragma unroll
  for (int t = 0; t < 4; ++t) boff[t] = col * 128 + (((t * 4 + quad) ^ col)) * 8;

  const char* cur = (const char*)xs + (size_t)jbase * 256;  // advances 4KB/tile
  auto stage = [&](int so) {
#pragma unroll
    for (int p = 0; p < 4; ++p)
      __builtin_amdgcn_global_load_lds(
          (const __attribute__((address_space(1))) void*)(uintptr_t)(cur + offp[p]),
          (__attribute__((address_space(3))) void*)(uintptr_t)(ldsb + so + p * 1024 +
                                                              lane * 16),
          16, 0, 0);
    cur += 4096;
  };

  float Z[4][4] = {}, U[4][4] = {}, V0[4][4] = {};

  stage(0);
  stage(4096);
  int co = 0;  // consume-buffer byte offset, cycles 0 -> 4096 -> 8192
  for (int t = 0; t < 32; ++t) {
    if (t < 30) {
      int so = (co >= 4096) ? co - 4096 : co + 8192;  // ring slot t+2
      stage(so);
      asm volatile("s_waitcnt vmcnt(8)" ::: "memory");  // tile t's batch done
    } else if (t == 30) {
      asm volatile("s_waitcnt vmcnt(4)" ::: "memory");
    } else {
      asm volatile("s_waitcnt vmcnt(0)" ::: "memory");
    }
    const short* tp = (const short*)(ldsb + co);
    short8 b0 = *(const short8*)(tp + boff[0]);
    short8 b1 = *(const short8*)(tp + boff[1]);
    short8 b2 = *(const short8*)(tp + boff[2]);
    short8 b3 = *(const short8*)(tp + boff[3]);
    float4v c0 = {0.f, 0.f, 0.f, 0.f}, c1 = {0.f, 0.f, 0.f, 0.f};
    float4v c2 = {0.f, 0.f, 0.f, 0.f}, c3 = {0.f, 0.f, 0.f, 0.f};
    c0 = __builtin_amdgcn_mfma_f32_16x16x32_bf16(afrag[0][0], b0, c0, 0, 0, 0);
    c1 = __builtin_amdgcn_mfma_f32_16x16x32_bf16(afrag[1][0], b0, c1, 0, 0, 0);
    c2 = __builtin_amdgcn_mfma_f32_16x16x32_bf16(afrag[2][0], b0, c2, 0, 0, 0);
    c3 = __builtin_amdgcn_mfma_f32_16x16x32_bf16(afrag[3][0], b0, c3, 0, 0, 0);
    c0 = __builtin_amdgcn_mfma_f32_16x16x32_bf16(afrag[0][1], b1, c0, 0, 0, 0);
    c1 = __builtin_amdgcn_mfma_f32_16x16x32_bf16(afrag[1][1], b1, c1, 0, 0, 0);
    c2 = __builtin_amdgcn_mfma_f32_16x16x32_bf16(afrag[2][1], b1, c2, 0, 0, 0);
    c3 = __builtin_amdgcn_mfma_f32_16x16x32_bf16(afrag[3][1], b1, c3, 0, 0, 0);
    c0 = __builtin_amdgcn_mfma_f32_16x16x32_bf16(afrag[0][2], b2, c0, 0, 0, 0);
    c1 = __builtin_amdgcn_mfma_f32_16x16x32_bf16(afrag[1][2], b2, c1, 0, 0, 0);
    c2 = __builtin_amdgcn_mfma_f32_16x16x32_bf16(afrag[2][2], b2, c2, 0, 0, 0);
    c3 = __builtin_amdgcn_mfma_f32_16x16x32_bf16(afrag[3][2], b2, c3, 0, 0, 0);
    c0 = __builtin_amdgcn_mfma_f32_16x16x32_bf16(afrag[0][3], b3, c0, 0, 0, 0);
    c1 = __builtin_amdgcn_mfma_f32_16x16x32_bf16(afrag[1][3], b3, c1, 0, 0, 0);
    c2 = __builtin_amdgcn_mfma_f32_16x16x32_bf16(afrag[2][3], b3, c2, 0, 0, 0);
    c3 = __builtin_amdgcn_mfma_f32_16x16x32_bf16(afrag[3][3], b3, c3, 0, 0, 0);
    float mm = ((mk >> t) & 1u) ? 1.f : 0.f;  // col-class mask (per lane)
#pragma unroll
    for (int r = 0; r < 4; ++r) {  // C/D: col=lane&15, row=quad*4+r (m89)
      float l0 = c0[r], e0 = EXP2(l0);  // log2-domain: l2<=20.6, fp32-safe
      Z[0][r] += e0; U[0][r] += e0 * l0; V0[0][r] += mm * e0;
      float l1 = c1[r], e1 = EXP2(l1);
      Z[1][r] += e1; U[1][r] += e1 * l1; V0[1][r] += mm * e1;
      float l2 = c2[r], e2 = EXP2(l2);
      Z[2][r] += e2; U[2][r] += e2 * l2; V0[2][r] += mm * e2;
      float l3 = c3[r], e3 = EXP2(l3);
      Z[3][r] += e3; U[3][r] += e3 * l3; V0[3][r] += mm * e3;
    }
    co = (co == 8192) ? 0 : co + 4096;
  }

  // flush: reduce across the 16 col-lanes, then 3 atomics per row
#pragma unroll
  for (int s = 0; s < 4; ++s)
#pragma unroll
    for (int r = 0; r < 4; ++r) {
#pragma unroll
      for (int off = 1; off < 16; off <<= 1) {
        Z[s][r] += __shfl_xor(Z[s][r], off);
        U[s][r] += __shfl_xor(U[s][r], off);
        V0[s][r] += __shfl_xor(V0[s][r], off);
      }
      if (col == 0) {
        int row = rowbase + s * 16 + quad * 4 + r;
        float v = (label[row] == 0) ? V0[s][r] : (Z[s][r] - V0[s][r]);
        atomicAdd(&Zr[row], Z[s][r]);
        atomicAdd(&Ur[row], U[s][r] * 0.6931471805599453f);  // log2 -> nats
        atomicAdd(&Vr[row], v);
      }
    }
}

// K4: per-row loss. S,T via closed-form dots with class sums; M and log(Zq) cancel.
__global__ __launch_bounds__(256) void k_final(const float* __restrict__ xnf,
                                               const int* __restrict__ label,
                                               const float* __restrict__ scale,
                                               const float* __restrict__ gh,
                                               const int* __restrict__ cnt,
                                               const float* __restrict__ Zr,
                                               const float* __restrict__ Ur,
                                               const float* __restrict__ Vr,
                                               float* __restrict__ out) {
  __shared__ float bsum[4];
  int tid = threadIdx.x, wave = tid >> 6, lane = tid & 63;
  float se = __expf(scale[0]);
  float h0a = gh[2 * lane], h0b = gh[2 * lane + 1];
  float h1a = gh[128 + 2 * lane], h1b = gh[128 + 2 * lane + 1];
  float ga = h0a + h1a, gb = h0b + h1b;  // g = h0 + h1
  float c0 = (float)cnt[0], c1 = (float)cnt[1];
  float local = 0.f;
  int rbase = blockIdx.x * 32 + wave * 8;
  for (int r = 0; r < 8; ++r) {
    int row = rbase + r;
    float2 x = *(const float2*)&xnf[row * DD + lane * 2];
    int lab = label[row];
    float sg = x.x * ga + x.y * gb;
    float sh_ = (lab == 0) ? (x.x * h0a + x.y * h0b) : (x.x * h1a + x.y * h1b);
    for (int off = 32; off; off >>= 1) {
      sg += __shfl_xor(sg, off);
      sh_ += __shfl_xor(sh_, off);
    }
    if (lane == 0) {
      float cc = (lab == 0) ? c0 : c1;
      float a = __expf(1.f / cc);
      float Zq = cc * a + ((float)BS - cc);
      float S = se * sg, T = se * sh_;
      float Z = Zr[row], U = Ur[row], V = Vr[row];
      // loss_i = a/Zq - (S+(a-1)T)/Zq + U/Z - V/(c*Z)   (M_i, log Zq cancelled)
      local += a / Zq - (S + (a - 1.f) * T) / Zq + U / Z - V / (cc * Z);
    }
  }
  if (lane == 0) bsum[wave] = local;
  __syncthreads();
  if (tid == 0) {
    float s = bsum[0] + bsum[1] + bsum[2] + bsum[3];
    atomicAdd(out, s * (0.5f / (float)BS));
  }
}

extern "C" void kernel_launch(void* const* d_in, const int* in_sizes, int n_in,
                              void* d_out, int out_size, void* d_ws, size_t ws_size,
                              hipStream_t stream) {
  const float* data = (const float*)d_in[0];
  const float* scale = (const float*)d_in[1];
  const int* label = (const int*)d_in[2];
  char* ws = (char*)d_ws;
  // ws layout (bytes):
  //   0        xnb  bf16[8192*128]   2 MB
  //   2097152  xnf  f32 [8192*128]   4 MB
  //   6291456  Zr   f32 [8192]
  //   6324224  Ur   f32 [8192]
  //   6356992  Vr   f32 [8192]
  //   6389760  gh   f32 [256]  (h0[128], h1[128])
  //   6390784  cnt  int [2]
  unsigned short* xnb = (unsigned short*)ws;
  unsigned int* xnb32 = (unsigned int*)ws;
  float* xnf = (float*)(ws + 2097152);
  float* Zr = (float*)(ws + 6291456);
  float* Ur = (float*)(ws + 6324224);
  float* Vr = (float*)(ws + 6356992);
  float* gh = (float*)(ws + 6389760);
  int* cnt = (int*)(ws + 6390784);

  // gh+cnt only (1032 B); Zr/Ur/Vr + d_out are zeroed inside k_norm
  hipMemsetAsync(ws + 6389760, 0, 1032, stream);

  k_norm<<<256, 256, 0, stream>>>(data, label, xnb32, xnf, gh, cnt, Zr, Ur, Vr,
                                  (float*)d_out);
  k_main<<<2048, 64, 0, stream>>>(xnb, label, scale, Zr, Ur, Vr);
  k_final<<<256, 256, 0, stream>>>(xnf, label, scale, gh, cnt, Zr, Ur, Vr, (float*)d_out);
}